// Round 19
// baseline (257.709 us; speedup 1.0000x reference)
//
#include <hip/hip_runtime.h>
#include <hip/hip_bf16.h>
#include <math.h>

typedef __bf16 bf16;
typedef __bf16 bf16x8 __attribute__((ext_vector_type(8)));
typedef __bf16 bf16x4 __attribute__((ext_vector_type(4)));
typedef float  f32x4  __attribute__((ext_vector_type(4)));
typedef float  f32x16 __attribute__((ext_vector_type(16)));
typedef int    i32x4  __attribute__((ext_vector_type(4)));

typedef __attribute__((address_space(1))) void gvoid;
typedef __attribute__((address_space(3))) void lvoid;
#define GLOAD_LDS16(gp, lp) __builtin_amdgcn_global_load_lds((gvoid*)(gp), (lvoid*)(lp), 16, 0, 0)

typedef __attribute__((address_space(3))) bf16x8 as3_bf16x8;
typedef __attribute__((address_space(3))) bf16   as3_bf16;
__device__ __forceinline__ bf16x8 lds_rd8(const void* p) {
  return *(const as3_bf16x8*)p;
}
__device__ __forceinline__ void lds_wr8(void* p, bf16x8 v) {
  *(as3_bf16x8*)p = v;
}
__device__ __forceinline__ void lds_wr1(void* p, bf16 v) {
  *(as3_bf16*)p = v;
}

// branch-free tanh-approx GELU (max |err| vs exact ~3e-3, << 0.13 budget)
__device__ __forceinline__ float gelu_fast(float x) {
  float y = 0.7978845608f * (x + 0.044715f * x * x * x);
  float e = exp2f(2.885390082f * y);
  return x * e / (e + 1.0f);
}

// ---------------------------------------------------------------------------
// prep: fused weight fp32->bf16 conversion (blocks 0..12287) + LN1 (12288+)
// ---------------------------------------------------------------------------
__global__ __launch_bounds__(256) void prep(
    const float* __restrict__ qkvw, const float* __restrict__ projw,
    const float* __restrict__ fc1w, const float* __restrict__ fc2w,
    bf16* __restrict__ qkvw_h, bf16* __restrict__ projw_h,
    bf16* __restrict__ fc1w_h, bf16* __restrict__ fc2w_h,
    const float* __restrict__ x, const float* __restrict__ g,
    const float* __restrict__ b, bf16* __restrict__ h1) {
  int blk = blockIdx.x;
  if (blk < 12288) {
    const float* in; bf16* out; int base;
    if (blk < 3072)      { in = qkvw; out = qkvw_h; base = blk; }
    else if (blk < 4096) { in = projw; out = projw_h; base = blk - 3072; }
    else if (blk < 8192) { in = fc1w; out = fc1w_h; base = blk - 4096; }
    else                 { in = fc2w; out = fc2w_h; base = blk - 8192; }
    int i = (base * 256 + threadIdx.x) * 4;
    f32x4 v = *(const f32x4*)(in + i);
    bf16x4 o;
    #pragma unroll
    for (int e = 0; e < 4; ++e) o[e] = (bf16)v[e];
    *(bf16x4*)(out + i) = o;
    return;
  }
  int w = threadIdx.x >> 6, l = threadIdx.x & 63;
  size_t row = (size_t)(blk - 12288) * 4 + w;
  const float* xr = x + row * 1024;
  float f[16];
  #pragma unroll
  for (int c = 0; c < 4; ++c) {
    f32x4 v = *(const f32x4*)(xr + c * 256 + l * 4);
    #pragma unroll
    for (int e = 0; e < 4; ++e) f[c * 4 + e] = v[e];
  }
  float s = 0.f, ss = 0.f;
  #pragma unroll
  for (int e = 0; e < 16; ++e) { s += f[e]; ss += f[e] * f[e]; }
  #pragma unroll
  for (int d = 1; d < 64; d <<= 1) { s += __shfl_xor(s, d); ss += __shfl_xor(ss, d); }
  float mean = s * (1.f / 1024.f);
  float var  = ss * (1.f / 1024.f) - mean * mean;
  float rstd = rsqrtf(var + 1e-5f);
  #pragma unroll
  for (int c = 0; c < 4; ++c) {
    f32x4 gv = *(const f32x4*)(g + c * 256 + l * 4);
    f32x4 bv = *(const f32x4*)(b + c * 256 + l * 4);
    bf16x4 ov;
    #pragma unroll
    for (int e = 0; e < 4; ++e)
      ov[e] = (bf16)((f[c * 4 + e] - mean) * rstd * gv[e] + bv[e]);
    *(bf16x4*)(h1 + row * 1024 + c * 256 + l * 4) = ov;
  }
}

// ---------------------------------------------------------------------------
// LayerNorm standalone (fallback path only)
// ---------------------------------------------------------------------------
__global__ __launch_bounds__(256) void ln_f32(const float* __restrict__ x,
    const float* __restrict__ g, const float* __restrict__ b, bf16* __restrict__ out) {
  int w = threadIdx.x >> 6, l = threadIdx.x & 63;
  size_t row = (size_t)blockIdx.x * 4 + w;
  const float* xr = x + row * 1024;
  float f[16];
  #pragma unroll
  for (int c = 0; c < 4; ++c) {
    f32x4 v = *(const f32x4*)(xr + c * 256 + l * 4);
    #pragma unroll
    for (int e = 0; e < 4; ++e) f[c * 4 + e] = v[e];
  }
  float s = 0.f, ss = 0.f;
  #pragma unroll
  for (int e = 0; e < 16; ++e) { s += f[e]; ss += f[e] * f[e]; }
  #pragma unroll
  for (int d = 1; d < 64; d <<= 1) { s += __shfl_xor(s, d); ss += __shfl_xor(ss, d); }
  float mean = s * (1.f / 1024.f);
  float var  = ss * (1.f / 1024.f) - mean * mean;
  float rstd = rsqrtf(var + 1e-5f);
  #pragma unroll
  for (int c = 0; c < 4; ++c) {
    f32x4 gv = *(const f32x4*)(g + c * 256 + l * 4);
    f32x4 bv = *(const f32x4*)(b + c * 256 + l * 4);
    bf16x4 ov;
    #pragma unroll
    for (int e = 0; e < 4; ++e)
      ov[e] = (bf16)((f[c * 4 + e] - mean) * rstd * gv[e] + bv[e]);
    *(bf16x4*)(out + row * 1024 + c * 256 + l * 4) = ov;
  }
}

// ---------------------------------------------------------------------------
// 256x256 GEMM, minimum 2-phase template (r17/r18 verified).
// ---------------------------------------------------------------------------
#define SWZ(tp) ((tp) ^ ((((tp) >> 9) & 1) << 5))
#define STAGE(buf, op, half, kt_) do { \
    const char* gp_ = (const char*)((op) ? Wp : Ap); \
    int t0_ = (op) ? colBase : rowBase; \
    const int P_ = (op) ? 12 : 13; \
    _Pragma("unroll") for (int s_ = 0; s_ < 2; ++s_) { \
      int b14_ = w * 2048 + s_ * 1024; \
      int tb_ = ((b14_ >> P_) << (P_ + 1)) | ((half) << P_) | (b14_ & ((1 << P_) - 1)); \
      int tq_ = SWZ(tb_ + l * 16); \
      GLOAD_LDS16(gp_ + ((size_t)(t0_ + (tq_ >> 7)) * lda + (size_t)(kt_) * 64) * 2 + (tq_ & 127), \
                  smbase + (buf) * 65536 + (op) * 32768 + tb_); \
    } \
  } while (0)
#define STAGEFULL(buf, kt_) do { \
    STAGE(buf, 0, 0, kt_); STAGE(buf, 0, 1, kt_); \
    STAGE(buf, 1, 0, kt_); STAGE(buf, 1, 1, kt_); \
  } while (0)
#define LDA(buf, mi, kk) lds_rd8(smbase + (buf) * 65536 + \
    SWZ((wm * 128 + (mi) * 16 + lr) * 128 + (kk) * 64 + lg * 16))
#define LDB(buf, ni, kk) lds_rd8(smbase + (buf) * 65536 + 32768 + \
    SWZ((wn * 64 + (ni) * 16 + lr) * 128 + (kk) * 64 + lg * 16))
#define RD_A(buf, MI0) { _Pragma("unroll") for (int i_ = 0; i_ < 4; ++i_) \
    _Pragma("unroll") for (int k_ = 0; k_ < 2; ++k_) a[i_][k_] = LDA(buf, (MI0) + i_, k_); }
#define RD_B(buf, NI0) { _Pragma("unroll") for (int j_ = 0; j_ < 2; ++j_) \
    _Pragma("unroll") for (int k_ = 0; k_ < 2; ++k_) bq[(NI0) + j_][k_] = LDB(buf, (NI0) + j_, k_); }
#define MFMA16(MI0, NI0) do { __builtin_amdgcn_s_setprio(1); \
    _Pragma("unroll") for (int i_ = 0; i_ < 4; ++i_) \
    _Pragma("unroll") for (int j_ = 0; j_ < 2; ++j_) \
    _Pragma("unroll") for (int k_ = 0; k_ < 2; ++k_) \
      acc[(MI0) + i_][(NI0) + j_] = __builtin_amdgcn_mfma_f32_16x16x32_bf16( \
          a[i_][k_], bq[(NI0) + j_][k_], acc[(MI0) + i_][(NI0) + j_], 0, 0, 0); \
    __builtin_amdgcn_s_setprio(0); } while (0)
#define BARX() __builtin_amdgcn_s_barrier()
#define LGK0() asm volatile("s_waitcnt lgkmcnt(0)")
#define VM0()  asm volatile("s_waitcnt vmcnt(0)")

#define GTILE(CUR, NXT, tn, DOSTAGE) do { \
    if (DOSTAGE) { STAGEFULL(NXT, tn); } \
    RD_A(CUR, 0); RD_B(CUR, 0); RD_B(CUR, 2); \
    LGK0(); MFMA16(0, 0); MFMA16(0, 2); \
    RD_A(CUR, 4); \
    LGK0(); MFMA16(4, 0); MFMA16(4, 2); \
    VM0(); BARX(); \
  } while (0)

template<int ACT, int HASBIAS, typename TO>
__global__ __launch_bounds__(512, 1) void gemm256(const bf16* __restrict__ Ap,
    const bf16* __restrict__ Wp, const float* __restrict__ bias,
    TO* __restrict__ out, int lda, int N, int klen, int nbx, size_t outSlice) {
  __shared__ bf16 smem_[2][2][256 * 64];
  char* smbase = (char*)smem_;
  int tid = threadIdx.x, w = tid >> 6, l = tid & 63, lr = l & 15, lg = l >> 4;
  int wm = w >> 2, wn = w & 3;
  int q = gridDim.x >> 3;
  int wg = ((int)blockIdx.x & 7) * q + ((int)blockIdx.x >> 3);
  int rowBase = (wg / nbx) * 256, colBase = (wg % nbx) * 256;
  Ap += (size_t)blockIdx.y * klen;
  Wp += (size_t)blockIdx.y * klen;
  out += (size_t)blockIdx.y * outSlice;

  f32x4 acc[8][4];
  const f32x4 fz = {0.f, 0.f, 0.f, 0.f};
  #pragma unroll
  for (int i = 0; i < 8; ++i)
    #pragma unroll
    for (int j = 0; j < 4; ++j) acc[i][j] = fz;
  bf16x8 a[4][2], bq[4][2];
  int nkt = klen >> 6;

  STAGEFULL(0, 0);
  VM0(); BARX();

  for (int t = 0; t < nkt; t += 2) {
    GTILE(0, 1, t + 1, true);
    GTILE(1, 0, t + 2, (t + 2 < nkt));
  }

  #pragma unroll
  for (int ni = 0; ni < 4; ++ni) {
    int col = colBase + wn * 64 + ni * 16 + lr;
    float bv = HASBIAS ? bias[col] : 0.f;
    #pragma unroll
    for (int mi = 0; mi < 8; ++mi) {
      #pragma unroll
      for (int jj = 0; jj < 4; ++jj) {
        int row2 = rowBase + wm * 128 + mi * 16 + lg * 4 + jj;
        float v = acc[mi][ni][jj] + bv;
        if constexpr (ACT == 1) v = gelu_fast(v);
        out[(size_t)row2 * N + col] = (TO)v;
      }
    }
  }
}

// ---------------------------------------------------------------------------
// proj reduce + residual + LN2 fused
// ---------------------------------------------------------------------------
__global__ __launch_bounds__(256) void projred_ln(const bf16* __restrict__ part,
    const float* __restrict__ x, const float* __restrict__ pb,
    const float* __restrict__ g, const float* __restrict__ bb,
    float* __restrict__ x1, bf16* __restrict__ h2) {
  int w = threadIdx.x >> 6, l = threadIdx.x & 63;
  size_t row = (size_t)blockIdx.x * 4 + w;
  size_t rb = row * 1024;
  float f[16];
  #pragma unroll
  for (int c = 0; c < 4; ++c) {
    int off = c * 256 + l * 4;
    f32x4 v = *(const f32x4*)(x + rb + off);
    v += *(const f32x4*)(pb + off);
    #pragma unroll
    for (int sl = 0; sl < 4; ++sl) {
      bf16x4 pv = *(const bf16x4*)(part + (size_t)sl * 4194304 + rb + off);
      #pragma unroll
      for (int e = 0; e < 4; ++e) v[e] += (float)pv[e];
    }
    *(f32x4*)(x1 + rb + off) = v;
    #pragma unroll
    for (int e = 0; e < 4; ++e) f[c * 4 + e] = v[e];
  }
  float s = 0.f, ss = 0.f;
  #pragma unroll
  for (int e = 0; e < 16; ++e) { s += f[e]; ss += f[e] * f[e]; }
  #pragma unroll
  for (int d = 1; d < 64; d <<= 1) { s += __shfl_xor(s, d); ss += __shfl_xor(ss, d); }
  float mean = s * (1.f / 1024.f);
  float var  = ss * (1.f / 1024.f) - mean * mean;
  float rstd = rsqrtf(var + 1e-5f);
  #pragma unroll
  for (int c = 0; c < 4; ++c) {
    int off = c * 256 + l * 4;
    f32x4 gv = *(const f32x4*)(g + off);
    f32x4 bv = *(const f32x4*)(bb + off);
    bf16x4 ov;
    #pragma unroll
    for (int e = 0; e < 4; ++e)
      ov[e] = (bf16)((f[c * 4 + e] - mean) * rstd * gv[e] + bv[e]);
    *(bf16x4*)(h2 + rb + off) = ov;
  }
}

// ---------------------------------------------------------------------------
// fc2 reduce: out = x1 + bias + sum of 4 bf16 K-slice partials
// ---------------------------------------------------------------------------
__global__ __launch_bounds__(256) void fc2_red(const bf16* __restrict__ part,
    const float* __restrict__ x1, const float* __restrict__ bias,
    float* __restrict__ out) {
  int i = (blockIdx.x * 256 + threadIdx.x) * 4;
  f32x4 s = *(const f32x4*)(x1 + i);
  s += *(const f32x4*)(bias + (i & 1023));
  #pragma unroll
  for (int k = 0; k < 4; ++k) {
    bf16x4 pv = *(const bf16x4*)(part + (size_t)k * 4194304 + i);
    #pragma unroll
    for (int e = 0; e < 4; ++e) s[e] += (float)pv[e];
  }
  *(f32x4*)(out + i) = s;
}

// ---------------------------------------------------------------------------
// m97-structure GEMM (fallback path only)
// ---------------------------------------------------------------------------
template<int ACT, int HASRES, typename TO>
__global__ __launch_bounds__(256) void gemm_bt(const bf16* __restrict__ A,
    const bf16* __restrict__ W, const float* __restrict__ bias,
    const float* __restrict__ res, TO* __restrict__ out, int M, int N, int K) {
  __shared__ bf16 As[128 * 32];
  __shared__ bf16 Bs[128 * 32];
  int tid = threadIdx.x;
  int w = tid >> 6, l = tid & 63;
  int lr = l & 15, lg = l >> 4;
  int wm = w >> 1, wn = w & 1;
  int rowBase = blockIdx.y * 128;
  int colBase = blockIdx.x * 128;
  f32x4 acc[4][4];
  const f32x4 fz = {0.f, 0.f, 0.f, 0.f};
  #pragma unroll
  for (int i = 0; i < 4; ++i)
    #pragma unroll
    for (int j = 0; j < 4; ++j) acc[i][j] = fz;
  for (int kt = 0; kt < K; kt += 32) {
    __syncthreads();
    #pragma unroll
    for (int j = 0; j < 2; ++j) {
      int u = (w * 2 + j) * 64 + l;
      int r = u >> 2, cb = (u & 3) * 8;
      GLOAD_LDS16(A + (size_t)(rowBase + r) * K + kt + cb, As + (w * 2 + j) * 512);
      GLOAD_LDS16(W + (size_t)(colBase + r) * K + kt + cb, Bs + (w * 2 + j) * 512);
    }
    __syncthreads();
    bf16x8 af[4], bfr[4];
    #pragma unroll
    for (int mi = 0; mi < 4; ++mi)
      af[mi] = lds_rd8(As + (wm * 64 + mi * 16 + lr) * 32 + lg * 8);
    #pragma unroll
    for (int ni = 0; ni < 4; ++ni)
      bfr[ni] = lds_rd8(Bs + (wn * 64 + ni * 16 + lr) * 32 + lg * 8);
    #pragma unroll
    for (int mi = 0; mi < 4; ++mi)
      #pragma unroll
      for (int ni = 0; ni < 4; ++ni)
        acc[mi][ni] = __builtin_amdgcn_mfma_f32_16x16x32_bf16(af[mi], bfr[ni], acc[mi][ni], 0, 0, 0);
  }
  #pragma unroll
  for (int ni = 0; ni < 4; ++ni) {
    int col = colBase + wn * 64 + ni * 16 + lr;
    float bv = bias[col];
    #pragma unroll
    for (int mi = 0; mi < 4; ++mi) {
      #pragma unroll
      for (int jj = 0; jj < 4; ++jj) {
        int row2 = rowBase + wm * 64 + mi * 16 + lg * 4 + jj;
        float v = acc[mi][ni][jj] + bv;
        if constexpr (ACT == 1) v = gelu_fast(v);
        if constexpr (HASRES)   v += res[(size_t)row2 * N + col];
        out[(size_t)row2 * N + col] = (TO)v;
      }
    }
  }
}

// ---------------------------------------------------------------------------
// Flash attention v9: v8 body, optionally split-KV x2 (SPLIT=1): grid 1024
// (4 blocks/CU -> 4 waves/SIMD fill), each block does 16 KV-tiles, writes
// UNNORMALIZED fp32 O-partial + per-q sum. Max-free softmax => partials
// combine by pure addition in attn_merge (no LSE weights).
// ---------------------------------------------------------------------------
#define MKFRAG(S, T, OUT) do { \
    int a_, b_, c_, d_; \
    asm("v_cvt_pk_bf16_f32 %0, %1, %2" : "=v"(a_) : "v"((S)[8*(T)+0]), "v"((S)[8*(T)+1])); \
    asm("v_cvt_pk_bf16_f32 %0, %1, %2" : "=v"(b_) : "v"((S)[8*(T)+4]), "v"((S)[8*(T)+5])); \
    asm("v_cvt_pk_bf16_f32 %0, %1, %2" : "=v"(c_) : "v"((S)[8*(T)+2]), "v"((S)[8*(T)+3])); \
    asm("v_cvt_pk_bf16_f32 %0, %1, %2" : "=v"(d_) : "v"((S)[8*(T)+6]), "v"((S)[8*(T)+7])); \
    asm("v_permlane32_swap_b32 %0, %1" : "+v"(a_), "+v"(b_)); \
    asm("v_permlane32_swap_b32 %0, %1" : "+v"(c_), "+v"(d_)); \
    i32x4 wv_ = {a_, c_, b_, d_}; \
    OUT = __builtin_bit_cast(bf16x8, wv_); \
  } while (0)

#define ATILE(BO, DOLOAD, DOSTAGE) do { \
    if (DOLOAD) { \
      kg0 = *(const bf16x8*)kp0; kp0 += step; \
      kg1 = *(const bf16x8*)kp1; kp1 += step; \
      vg0 = *(const bf16x8*)vp0; \
      vg1 = *(const bf16x8*)(vp0 + 32); vp0 += step; \
    } \
    bf16x8 ka[2][4]; \
    _Pragma("unroll") for (int kb = 0; kb < 2; ++kb) \
      _Pragma("unroll") for (int dk = 0; dk < 4; ++dk) \
        ka[kb][dk] = lds_rd8(abase + (BO) + kb * 4096 + doff[dk]); \
    f32x16 sc0 = zz, sc1 = zz; \
    __builtin_amdgcn_s_setprio(1); \
    _Pragma("unroll") for (int dk = 0; dk < 4; ++dk) { \
      sc0 = __builtin_amdgcn_mfma_f32_32x32x16_bf16(ka[0][dk], qf[dk], sc0, 0, 0, 0); \
      sc1 = __builtin_amdgcn_mfma_f32_32x32x16_bf16(ka[1][dk], qf[dk], sc1, 0, 0, 0); \
    } \
    __builtin_amdgcn_s_setprio(0); \
    _Pragma("unroll") for (int r = 0; r < 16; ++r) sc0[r] = exp2f(sc0[r]); \
    _Pragma("unroll") for (int r = 0; r < 16; ++r) sc1[r] = exp2f(sc1[r]); \
    { \
      float t0_ = (sc0[0] + sc0[1]) + (sc0[2] + sc0[3]); \
      float t1_ = (sc0[4] + sc0[5]) + (sc0[6] + sc0[7]); \
      float t2_ = (sc0[8] + sc0[9]) + (sc0[10] + sc0[11]); \
      float t3_ = (sc0[12] + sc0[13]) + (sc0[14] + sc0[15]); \
      float t4_ = (sc1[0] + sc1[1]) + (sc1[2] + sc1[3]); \
      float t5_ = (sc1[4] + sc1[5]) + (sc1[6] + sc1[7]); \
      float t6_ = (sc1[8] + sc1[9]) + (sc1[10] + sc1[11]); \
      float t7_ = (sc1[12] + sc1[13]) + (sc1[14] + sc1[15]); \
      float rs = ((t0_ + t1_) + (t2_ + t3_)) + ((t4_ + t5_) + (t6_ + t7_)); \
      rs += __shfl_xor(rs, 32); \
      srow += rs; \
    } \
    bf16x8 pa0, pa1, pa2, pa3; \
    MKFRAG(sc0, 0, pa0); MKFRAG(sc0, 1, pa1); \
    MKFRAG(sc1, 0, pa2); MKFRAG(sc1, 1, pa3); \
    bf16x8 vb[2][4]; \
    _Pragma("unroll") for (int db = 0; db < 2; ++db) \
      _Pragma("unroll") for (int ks = 0; ks < 4; ++ks) \
        vb[db][ks] = lds_rd8(vbase + (BO) + db * 4096 + doff[ks]); \
    __builtin_amdgcn_s_setprio(1); \
    oa0 = __builtin_amdgcn_mfma_f32_32x32x16_bf16(pa0, vb[0][0], oa0, 0, 0, 0); \
    oa0 = __builtin_amdgcn_mfma_f32_32x32x16_bf16(pa1, vb[0][1], oa0, 0, 0, 0); \
    oa0 = __builtin_amdgcn_mfma_f32_32x32x16_bf16(pa2, vb[0][2], oa0, 0, 0, 0); \
    oa0 = __builtin_amdgcn_mfma_f32_32x32x16_bf16(pa3, vb[0][3], oa0, 0, 0, 0); \
    oa1 = __builtin_amdgcn_mfma_f32_32x32x16_bf16(pa0, vb[1][0], oa1, 0, 0, 0); \
    oa1 = __builtin_amdgcn_mfma_f32_32x32x16_bf16(pa1, vb[1][1], oa1, 0, 0, 0); \
    oa1 = __builtin_amdgcn_mfma_f32_32x32x16_bf16(pa2, vb[1][2], oa1, 0, 0, 0); \
    oa1 = __builtin_amdgcn_mfma_f32_32x32x16_bf16(pa3, vb[1][3], oa1, 0, 0, 0); \
    __builtin_amdgcn_s_setprio(0); \
    if (DOSTAGE) { \
      lds_wr8(ksw + ((BO) ^ 8192), kg0); \
      lds_wr8(ksw + 4096 + ((BO) ^ 8192), kg1); \
      _Pragma("unroll") for (int e = 0; e < 8; ++e) { \
        lds_wr1(vtw + ((BO) ^ 8192) + e * 128 + (l2 ^ (e << 4)), vg0[e]); \
        lds_wr1(vtw + ((BO) ^ 8192) + 4096 + e * 128 + (l2 ^ (e << 4)), vg1[e]); \
      } \
      __syncthreads(); \
    } \
  } while (0)

template<int SPLIT>
__global__ __launch_bounds__(256) void attn_kernel(const bf16* __restrict__ qkv,
    bf16* __restrict__ o, float* __restrict__ opart, float* __restrict__ ssum) {
  const int Nn = 2048, C3 = 3072;
  int tid = threadIdx.x, w = tid >> 6, l = tid & 63;
  int q32 = l & 31, hi = l >> 5, hi4 = hi * 4;
  int lin = blockIdx.x;
  int wg, half;
  if constexpr (SPLIT) {              // 1024 blocks = 8 XCD x 128
    wg = (lin & 7) * 128 + (lin >> 3);
    half = wg >> 9; wg &= 511;
  } else {                            // 512 blocks = 8 XCD x 64
    wg = (lin & 7) * 64 + (lin >> 3);
    half = 0;
  }
  int qb = wg & 15, bh = wg >> 4;
  int b = bh >> 4, h = bh & 15;
  size_t hb = (size_t)b * Nn * C3 + h * 64;
  const bf16* Qp = qkv + hb;
  __shared__ bf16 Ks[2][64 * 64];
  __shared__ bf16 Vt[2][64 * 64];

  int q0w = qb * 128 + w * 32;
  bf16x8 qf[4];
  {
    const bf16* qrow = Qp + (size_t)(q0w + q32) * C3 + 8 * hi;
    #pragma unroll
    for (int dk = 0; dk < 4; ++dk) {
      bf16x8 t = *(const bf16x8*)(qrow + 16 * dk);
      #pragma unroll
      for (int e = 0; e < 8; ++e) qf[dk][e] = (bf16)((float)t[e] * 0.18033688f);
    }
  }

  int swz = (l & 7) << 4;
  int kr0 = tid >> 3, c80 = (tid & 7) * 8;
  char* ksw = (char*)Ks + kr0 * 128 + ((c80 * 2) ^ ((kr0 & 7) << 4));
  char* vtw = (char*)Vt + w * 1024;
  int l2 = l * 2;
  const char* abase = (const char*)Ks + q32 * 128;
  const char* vbase = (const char*)Vt + q32 * 128;
  int doff[4];
  #pragma unroll
  for (int dk = 0; dk < 4; ++dk) doff[dk] = (32 * dk + 16 * hi) ^ swz;

  const int step = 64 * C3;
  const bf16* kp0 = qkv + hb + 1024 + (size_t)kr0 * C3 + c80
                    + (size_t)(SPLIT ? half * 16 : 0) * step;
  const bf16* kp1 = kp0 + (size_t)32 * C3;
  const bf16* vp0 = qkv + hb + 2048 + (size_t)l * C3 + w * 8
                    + (size_t)(SPLIT ? half * 16 : 0) * step;

  f32x16 zz;
  #pragma unroll
  for (int i = 0; i < 16; ++i) zz[i] = 0.f;
  f32x16 oa0 = zz, oa1 = zz;
  float srow = 0.f;

  bf16x8 kg0 = *(const bf16x8*)kp0; kp0 += step;
  bf16x8 kg1 = *(const bf16x8*)kp1; kp1 += step;
  bf16x8 vg0 = *(const bf16x8*)vp0;
  bf16x8 vg1 = *(const bf16x8*)(vp0 + 32); vp0 += step;
  lds_wr8(ksw, kg0);
  lds_wr8(ksw + 4096, kg1);
  #pragma unroll
  for (int e = 0; e < 8; ++e) {
    lds_wr1(vtw + e * 128 + (l2 ^ (e << 4)), vg0[e]);
    lds_wr1(vtw + 4096 + e * 128 + (l2 ^ (e << 4)), vg1[e]);
  }
  __syncthreads();

  const int NT = SPLIT ? 8 : 16;
  for (int tt = 0; tt < NT; ++tt) {
    ATILE(0,    true,         true);
    ATILE(8192, tt < NT - 1,  tt < NT - 1);
  }

  size_t obase = ((size_t)b * Nn + q0w + hi4) * 1024 + h * 64 + q32;
  if constexpr (SPLIT) {
    float* op = opart + (size_t)half * 4194304 + obase;
    #pragma unroll
    for (int r = 0; r < 16; ++r) {
      const int cr = (r & 3) + 8 * (r >> 2);
      op[(size_t)cr * 1024]      = oa0[r];
      op[(size_t)cr * 1024 + 32] = oa1[r];
    }
    if (l < 32)
      ssum[half * 65536 + b * 2048 + q0w + q32] = srow;
  } else {
    float inv = 1.f / srow;
    bf16* ob = o + obase;
    #pragma unroll
    for (int r = 0; r < 16; ++r) {
      const int cr = (r & 3) + 8 * (r >> 2);
      float invr = __shfl(inv, cr + hi4);
      ob[(size_t)cr * 1024]      = (bf16)(oa0[r] * invr);
      ob[(size_t)cr * 1024 + 32] = (bf16)(oa1[r] * invr);
    }
  }
}

// ---------------------------------------------------------------------------
// attn merge (max-free): o = (p0 + p1) / (s0 + s1)
// ---------------------------------------------------------------------------
__global__ __launch_bounds__(256) void attn_merge(const float* __restrict__ opart,
    const float* __restrict__ ssum, bf16* __restrict__ o) {
  int i = blockIdx.x * 256 + threadIdx.x;        // 1,048,576 groups of 4
  size_t off = (size_t)i * 4;
  int bq = (int)(off >> 10);                     // b*2048 + q
  f32x4 a0 = *(const f32x4*)(opart + off);
  f32x4 a1 = *(const f32x4*)(opart + 4194304 + off);
  float inv = 1.f / (ssum[bq] + ssum[65536 + bq]);
  bf16x4 ov;
  #pragma unroll
  for (int e = 0; e < 4; ++e) ov[e] = (bf16)((a0[e] + a1[e]) * inv);
  *(bf16x4*)(o + off) = ov;
}

// ---------------------------------------------------------------------------
extern "C" void kernel_launch(void* const* d_in, const int* in_sizes, int n_in,
                              void* d_out, int out_size, void* d_ws, size_t ws_size,
                              hipStream_t stream) {
  (void)in_sizes; (void)n_in; (void)out_size;
  const float* x     = (const float*)d_in[0];
  const float* ln1g  = (const float*)d_in[1];
  const float* ln1b  = (const float*)d_in[2];
  const float* qkvw  = (const float*)d_in[3];
  const float* qkvb  = (const float*)d_in[4];
  const float* projw = (const float*)d_in[5];
  const float* projb = (const float*)d_in[6];
  const float* ln2g  = (const float*)d_in[7];
  const float* ln2b  = (const float*)d_in[8];
  const float* fc1w  = (const float*)d_in[9];
  const float* fc1b  = (const float*)d_in[10];
  const float* fc2w  = (const float*)d_in[11];
  const float* fc2b  = (const float*)d_in[12];

  char* ws = (char*)d_ws;
  bf16*  qkvw_h = (bf16*)(ws);                    // [0,  6M)
  bf16*  projw_h= (bf16*)(ws + (6ull  << 20));    // [6,  8M)
  bf16*  fc1w_h = (bf16*)(ws + (8ull  << 20));    // [8, 16M)
  bf16*  fc2w_h = (bf16*)(ws + (16ull << 20));    // [16,24M)
  bf16*  h1     = (bf16*)(ws + (24ull << 20));    // [24,32M)  (reused for h2)
  bf16*  qkv    = (bf16*)(ws + (32ull << 20));    // [32,64M)  (reused for ffn)
  bf16*  ov     = (bf16*)(ws + (64ull << 20));    // [64,72M)
  float* x1     = (float*)(ws + (72ull << 20));   // [72,88M)  fp32 residual trunk
  bf16*  parts  = (bf16*)(ws + (96ull << 20));    // [96,128M) proj/fc2 partials
  float* opart  = (float*)(ws + (96ull << 20));   // [96,130M) attn O partials (dead before parts)
  float* ssum   = (float*)(ws + (130ull << 20));  // [130,130.5M)
  bf16*  h2  = h1;
  bf16*  ffn = qkv;
  bool big = ws_size >= (160ull << 20);

  const int M = 4096;
  prep<<<dim3(12288 + 1024), 256, 0, stream>>>(qkvw, projw, fc1w, fc2w,
      qkvw_h, projw_h, fc1w_h, fc2w_h, x, ln1g, ln1b, h1);
  gemm256<0, 1, bf16><<<dim3(192), dim3(512), 0, stream>>>(
      h1, qkvw_h, qkvb, qkv, 1024, 3072, 1024, 12, 0);
  if (big) {
    attn_kernel<1><<<dim3(1024), 256, 0, stream>>>(qkv, nullptr, opart, ssum);
    attn_merge<<<dim3(4096), 256, 0, stream>>>(opart, ssum, ov);
    gemm256<0, 0, bf16><<<dim3(64, 4), dim3(512), 0, stream>>>(
        ov, projw_h, nullptr, parts, 1024, 1024, 256, 4, 4194304ull);
    projred_ln<<<dim3(1024), 256, 0, stream>>>(parts, x, projb, ln2g, ln2b, x1, h2);
  } else {
    attn_kernel<0><<<dim3(512), 256, 0, stream>>>(qkv, ov, nullptr, nullptr);
    gemm_bt<0, 1, float><<<dim3(8, 32), 256, 0, stream>>>(
        ov, projw_h, projb, x, x1, M, 1024, 1024);
    ln_f32<<<dim3(1024), 256, 0, stream>>>(x1, ln2g, ln2b, h2);
  }
  gemm256<1, 1, bf16><<<dim3(256), dim3(512), 0, stream>>>(
      h2, fc1w_h, fc1b, ffn, 1024, 4096, 1024, 16, 0);
  if (big) {
    gemm256<0, 0, bf16><<<dim3(64, 4), dim3(512), 0, stream>>>(
        ffn, fc2w_h, nullptr, parts, 4096, 1024, 1024, 4, 4194304ull);
    fc2_red<<<dim3(4096), 256, 0, stream>>>(parts, x1, fc2b, (float*)d_out);
  } else {
    gemm_bt<0, 1, float><<<dim3(8, 32), 256, 0, stream>>>(
        ffn, fc2w_h, fc2b, x1, (float*)d_out, M, 1024, 4096);
  }
}

// Round 20
// 249.933 us; speedup vs baseline: 1.0311x; 1.0311x over previous
//
#include <hip/hip_runtime.h>
#include <hip/hip_bf16.h>
#include <math.h>

typedef __bf16 bf16;
typedef __bf16 bf16x8 __attribute__((ext_vector_type(8)));
typedef __bf16 bf16x4 __attribute__((ext_vector_type(4)));
typedef float  f32x4  __attribute__((ext_vector_type(4)));
typedef float  f32x16 __attribute__((ext_vector_type(16)));
typedef int    i32x4  __attribute__((ext_vector_type(4)));

typedef __attribute__((address_space(1))) void gvoid;
typedef __attribute__((address_space(3))) void lvoid;
#define GLOAD_LDS16(gp, lp) __builtin_amdgcn_global_load_lds((gvoid*)(gp), (lvoid*)(lp), 16, 0, 0)

typedef __attribute__((address_space(3))) bf16x8 as3_bf16x8;
typedef __attribute__((address_space(3))) bf16   as3_bf16;
__device__ __forceinline__ bf16x8 lds_rd8(const void* p) {
  return *(const as3_bf16x8*)p;
}
__device__ __forceinline__ void lds_wr8(void* p, bf16x8 v) {
  *(as3_bf16x8*)p = v;
}
__device__ __forceinline__ void lds_wr1(void* p, bf16 v) {
  *(as3_bf16*)p = v;
}

// branch-free tanh-approx GELU (max |err| vs exact ~3e-3, << 0.13 budget)
__device__ __forceinline__ float gelu_fast(float x) {
  float y = 0.7978845608f * (x + 0.044715f * x * x * x);
  float e = exp2f(2.885390082f * y);
  return x * e / (e + 1.0f);
}

// ---------------------------------------------------------------------------
// prep: fused weight fp32->bf16 conversion (blocks 0..12287) + LN1 (12288+)
// ---------------------------------------------------------------------------
__global__ __launch_bounds__(256) void prep(
    const float* __restrict__ qkvw, const float* __restrict__ projw,
    const float* __restrict__ fc1w, const float* __restrict__ fc2w,
    bf16* __restrict__ qkvw_h, bf16* __restrict__ projw_h,
    bf16* __restrict__ fc1w_h, bf16* __restrict__ fc2w_h,
    const float* __restrict__ x, const float* __restrict__ g,
    const float* __restrict__ b, bf16* __restrict__ h1) {
  int blk = blockIdx.x;
  if (blk < 12288) {
    const float* in; bf16* out; int base;
    if (blk < 3072)      { in = qkvw; out = qkvw_h; base = blk; }
    else if (blk < 4096) { in = projw; out = projw_h; base = blk - 3072; }
    else if (blk < 8192) { in = fc1w; out = fc1w_h; base = blk - 4096; }
    else                 { in = fc2w; out = fc2w_h; base = blk - 8192; }
    int i = (base * 256 + threadIdx.x) * 4;
    f32x4 v = *(const f32x4*)(in + i);
    bf16x4 o;
    #pragma unroll
    for (int e = 0; e < 4; ++e) o[e] = (bf16)v[e];
    *(bf16x4*)(out + i) = o;
    return;
  }
  int w = threadIdx.x >> 6, l = threadIdx.x & 63;
  size_t row = (size_t)(blk - 12288) * 4 + w;
  const float* xr = x + row * 1024;
  float f[16];
  #pragma unroll
  for (int c = 0; c < 4; ++c) {
    f32x4 v = *(const f32x4*)(xr + c * 256 + l * 4);
    #pragma unroll
    for (int e = 0; e < 4; ++e) f[c * 4 + e] = v[e];
  }
  float s = 0.f, ss = 0.f;
  #pragma unroll
  for (int e = 0; e < 16; ++e) { s += f[e]; ss += f[e] * f[e]; }
  #pragma unroll
  for (int d = 1; d < 64; d <<= 1) { s += __shfl_xor(s, d); ss += __shfl_xor(ss, d); }
  float mean = s * (1.f / 1024.f);
  float var  = ss * (1.f / 1024.f) - mean * mean;
  float rstd = rsqrtf(var + 1e-5f);
  #pragma unroll
  for (int c = 0; c < 4; ++c) {
    f32x4 gv = *(const f32x4*)(g + c * 256 + l * 4);
    f32x4 bv = *(const f32x4*)(b + c * 256 + l * 4);
    bf16x4 ov;
    #pragma unroll
    for (int e = 0; e < 4; ++e)
      ov[e] = (bf16)((f[c * 4 + e] - mean) * rstd * gv[e] + bv[e]);
    *(bf16x4*)(h1 + row * 1024 + c * 256 + l * 4) = ov;
  }
}

// ---------------------------------------------------------------------------
// LayerNorm standalone (fallback path only)
// ---------------------------------------------------------------------------
__global__ __launch_bounds__(256) void ln_f32(const float* __restrict__ x,
    const float* __restrict__ g, const float* __restrict__ b, bf16* __restrict__ out) {
  int w = threadIdx.x >> 6, l = threadIdx.x & 63;
  size_t row = (size_t)blockIdx.x * 4 + w;
  const float* xr = x + row * 1024;
  float f[16];
  #pragma unroll
  for (int c = 0; c < 4; ++c) {
    f32x4 v = *(const f32x4*)(xr + c * 256 + l * 4);
    #pragma unroll
    for (int e = 0; e < 4; ++e) f[c * 4 + e] = v[e];
  }
  float s = 0.f, ss = 0.f;
  #pragma unroll
  for (int e = 0; e < 16; ++e) { s += f[e]; ss += f[e] * f[e]; }
  #pragma unroll
  for (int d = 1; d < 64; d <<= 1) { s += __shfl_xor(s, d); ss += __shfl_xor(ss, d); }
  float mean = s * (1.f / 1024.f);
  float var  = ss * (1.f / 1024.f) - mean * mean;
  float rstd = rsqrtf(var + 1e-5f);
  #pragma unroll
  for (int c = 0; c < 4; ++c) {
    f32x4 gv = *(const f32x4*)(g + c * 256 + l * 4);
    f32x4 bv = *(const f32x4*)(b + c * 256 + l * 4);
    bf16x4 ov;
    #pragma unroll
    for (int e = 0; e < 4; ++e)
      ov[e] = (bf16)((f[c * 4 + e] - mean) * rstd * gv[e] + bv[e]);
    *(bf16x4*)(out + row * 1024 + c * 256 + l * 4) = ov;
  }
}

// ---------------------------------------------------------------------------
// 256x256 GEMM, minimum 2-phase template (r17/r18 verified best).
// ---------------------------------------------------------------------------
#define SWZ(tp) ((tp) ^ ((((tp) >> 9) & 1) << 5))
#define STAGE(buf, op, half, kt_) do { \
    const char* gp_ = (const char*)((op) ? Wp : Ap); \
    int t0_ = (op) ? colBase : rowBase; \
    const int P_ = (op) ? 12 : 13; \
    _Pragma("unroll") for (int s_ = 0; s_ < 2; ++s_) { \
      int b14_ = w * 2048 + s_ * 1024; \
      int tb_ = ((b14_ >> P_) << (P_ + 1)) | ((half) << P_) | (b14_ & ((1 << P_) - 1)); \
      int tq_ = SWZ(tb_ + l * 16); \
      GLOAD_LDS16(gp_ + ((size_t)(t0_ + (tq_ >> 7)) * lda + (size_t)(kt_) * 64) * 2 + (tq_ & 127), \
                  smbase + (buf) * 65536 + (op) * 32768 + tb_); \
    } \
  } while (0)
#define STAGEFULL(buf, kt_) do { \
    STAGE(buf, 0, 0, kt_); STAGE(buf, 0, 1, kt_); \
    STAGE(buf, 1, 0, kt_); STAGE(buf, 1, 1, kt_); \
  } while (0)
#define LDA(buf, mi, kk) lds_rd8(smbase + (buf) * 65536 + \
    SWZ((wm * 128 + (mi) * 16 + lr) * 128 + (kk) * 64 + lg * 16))
#define LDB(buf, ni, kk) lds_rd8(smbase + (buf) * 65536 + 32768 + \
    SWZ((wn * 64 + (ni) * 16 + lr) * 128 + (kk) * 64 + lg * 16))
#define RD_A(buf, MI0) { _Pragma("unroll") for (int i_ = 0; i_ < 4; ++i_) \
    _Pragma("unroll") for (int k_ = 0; k_ < 2; ++k_) a[i_][k_] = LDA(buf, (MI0) + i_, k_); }
#define RD_B(buf, NI0) { _Pragma("unroll") for (int j_ = 0; j_ < 2; ++j_) \
    _Pragma("unroll") for (int k_ = 0; k_ < 2; ++k_) bq[(NI0) + j_][k_] = LDB(buf, (NI0) + j_, k_); }
#define MFMA16(MI0, NI0) do { __builtin_amdgcn_s_setprio(1); \
    _Pragma("unroll") for (int i_ = 0; i_ < 4; ++i_) \
    _Pragma("unroll") for (int j_ = 0; j_ < 2; ++j_) \
    _Pragma("unroll") for (int k_ = 0; k_ < 2; ++k_) \
      acc[(MI0) + i_][(NI0) + j_] = __builtin_amdgcn_mfma_f32_16x16x32_bf16( \
          a[i_][k_], bq[(NI0) + j_][k_], acc[(MI0) + i_][(NI0) + j_], 0, 0, 0); \
    __builtin_amdgcn_s_setprio(0); } while (0)
#define BARX() __builtin_amdgcn_s_barrier()
#define LGK0() asm volatile("s_waitcnt lgkmcnt(0)")
#define VM0()  asm volatile("s_waitcnt vmcnt(0)")

#define GTILE(CUR, NXT, tn, DOSTAGE) do { \
    if (DOSTAGE) { STAGEFULL(NXT, tn); } \
    RD_A(CUR, 0); RD_B(CUR, 0); RD_B(CUR, 2); \
    LGK0(); MFMA16(0, 0); MFMA16(0, 2); \
    RD_A(CUR, 4); \
    LGK0(); MFMA16(4, 0); MFMA16(4, 2); \
    VM0(); BARX(); \
  } while (0)

template<int ACT, int HASBIAS, typename TO>
__global__ __launch_bounds__(512, 1) void gemm256(const bf16* __restrict__ Ap,
    const bf16* __restrict__ Wp, const float* __restrict__ bias,
    TO* __restrict__ out, int lda, int N, int klen, int nbx, size_t outSlice) {
  __shared__ bf16 smem_[2][2][256 * 64];
  char* smbase = (char*)smem_;
  int tid = threadIdx.x, w = tid >> 6, l = tid & 63, lr = l & 15, lg = l >> 4;
  int wm = w >> 2, wn = w & 3;
  int q = gridDim.x >> 3;
  int wg = ((int)blockIdx.x & 7) * q + ((int)blockIdx.x >> 3);
  int rowBase = (wg / nbx) * 256, colBase = (wg % nbx) * 256;
  Ap += (size_t)blockIdx.y * klen;
  Wp += (size_t)blockIdx.y * klen;
  out += (size_t)blockIdx.y * outSlice;

  f32x4 acc[8][4];
  const f32x4 fz = {0.f, 0.f, 0.f, 0.f};
  #pragma unroll
  for (int i = 0; i < 8; ++i)
    #pragma unroll
    for (int j = 0; j < 4; ++j) acc[i][j] = fz;
  bf16x8 a[4][2], bq[4][2];
  int nkt = klen >> 6;

  STAGEFULL(0, 0);
  VM0(); BARX();

  for (int t = 0; t < nkt; t += 2) {
    GTILE(0, 1, t + 1, true);
    GTILE(1, 0, t + 2, (t + 2 < nkt));
  }

  #pragma unroll
  for (int ni = 0; ni < 4; ++ni) {
    int col = colBase + wn * 64 + ni * 16 + lr;
    float bv = HASBIAS ? bias[col] : 0.f;
    #pragma unroll
    for (int mi = 0; mi < 8; ++mi) {
      #pragma unroll
      for (int jj = 0; jj < 4; ++jj) {
        int row2 = rowBase + wm * 128 + mi * 16 + lg * 4 + jj;
        float v = acc[mi][ni][jj] + bv;
        if constexpr (ACT == 1) v = gelu_fast(v);
        out[(size_t)row2 * N + col] = (TO)v;
      }
    }
  }
}

// ---------------------------------------------------------------------------
// proj reduce + residual + LN2 fused
// ---------------------------------------------------------------------------
__global__ __launch_bounds__(256) void projred_ln(const bf16* __restrict__ part,
    const float* __restrict__ x, const float* __restrict__ pb,
    const float* __restrict__ g, const float* __restrict__ bb,
    float* __restrict__ x1, bf16* __restrict__ h2) {
  int w = threadIdx.x >> 6, l = threadIdx.x & 63;
  size_t row = (size_t)blockIdx.x * 4 + w;
  size_t rb = row * 1024;
  float f[16];
  #pragma unroll
  for (int c = 0; c < 4; ++c) {
    int off = c * 256 + l * 4;
    f32x4 v = *(const f32x4*)(x + rb + off);
    v += *(const f32x4*)(pb + off);
    #pragma unroll
    for (int sl = 0; sl < 4; ++sl) {
      bf16x4 pv = *(const bf16x4*)(part + (size_t)sl * 4194304 + rb + off);
      #pragma unroll
      for (int e = 0; e < 4; ++e) v[e] += (float)pv[e];
    }
    *(f32x4*)(x1 + rb + off) = v;
    #pragma unroll
    for (int e = 0; e < 4; ++e) f[c * 4 + e] = v[e];
  }
  float s = 0.f, ss = 0.f;
  #pragma unroll
  for (int e = 0; e < 16; ++e) { s += f[e]; ss += f[e] * f[e]; }
  #pragma unroll
  for (int d = 1; d < 64; d <<= 1) { s += __shfl_xor(s, d); ss += __shfl_xor(ss, d); }
  float mean = s * (1.f / 1024.f);
  float var  = ss * (1.f / 1024.f) - mean * mean;
  float rstd = rsqrtf(var + 1e-5f);
  #pragma unroll
  for (int c = 0; c < 4; ++c) {
    int off = c * 256 + l * 4;
    f32x4 gv = *(const f32x4*)(g + off);
    f32x4 bv = *(const f32x4*)(bb + off);
    bf16x4 ov;
    #pragma unroll
    for (int e = 0; e < 4; ++e)
      ov[e] = (bf16)((f[c * 4 + e] - mean) * rstd * gv[e] + bv[e]);
    *(bf16x4*)(h2 + rb + off) = ov;
  }
}

// ---------------------------------------------------------------------------
// fc2 reduce: out = x1 + bias + sum of 4 bf16 K-slice partials
// ---------------------------------------------------------------------------
__global__ __launch_bounds__(256) void fc2_red(const bf16* __restrict__ part,
    const float* __restrict__ x1, const float* __restrict__ bias,
    float* __restrict__ out) {
  int i = (blockIdx.x * 256 + threadIdx.x) * 4;
  f32x4 s = *(const f32x4*)(x1 + i);
  s += *(const f32x4*)(bias + (i & 1023));
  #pragma unroll
  for (int k = 0; k < 4; ++k) {
    bf16x4 pv = *(const bf16x4*)(part + (size_t)k * 4194304 + i);
    #pragma unroll
    for (int e = 0; e < 4; ++e) s[e] += (float)pv[e];
  }
  *(f32x4*)(out + i) = s;
}

// ---------------------------------------------------------------------------
// m97-structure GEMM (fallback path only)
// ---------------------------------------------------------------------------
template<int ACT, int HASRES, typename TO>
__global__ __launch_bounds__(256) void gemm_bt(const bf16* __restrict__ A,
    const bf16* __restrict__ W, const float* __restrict__ bias,
    const float* __restrict__ res, TO* __restrict__ out, int M, int N, int K) {
  __shared__ bf16 As[128 * 32];
  __shared__ bf16 Bs[128 * 32];
  int tid = threadIdx.x;
  int w = tid >> 6, l = tid & 63;
  int lr = l & 15, lg = l >> 4;
  int wm = w >> 1, wn = w & 1;
  int rowBase = blockIdx.y * 128;
  int colBase = blockIdx.x * 128;
  f32x4 acc[4][4];
  const f32x4 fz = {0.f, 0.f, 0.f, 0.f};
  #pragma unroll
  for (int i = 0; i < 4; ++i)
    #pragma unroll
    for (int j = 0; j < 4; ++j) acc[i][j] = fz;
  for (int kt = 0; kt < K; kt += 32) {
    __syncthreads();
    #pragma unroll
    for (int j = 0; j < 2; ++j) {
      int u = (w * 2 + j) * 64 + l;
      int r = u >> 2, cb = (u & 3) * 8;
      GLOAD_LDS16(A + (size_t)(rowBase + r) * K + kt + cb, As + (w * 2 + j) * 512);
      GLOAD_LDS16(W + (size_t)(colBase + r) * K + kt + cb, Bs + (w * 2 + j) * 512);
    }
    __syncthreads();
    bf16x8 af[4], bfr[4];
    #pragma unroll
    for (int mi = 0; mi < 4; ++mi)
      af[mi] = lds_rd8(As + (wm * 64 + mi * 16 + lr) * 32 + lg * 8);
    #pragma unroll
    for (int ni = 0; ni < 4; ++ni)
      bfr[ni] = lds_rd8(Bs + (wn * 64 + ni * 16 + lr) * 32 + lg * 8);
    #pragma unroll
    for (int mi = 0; mi < 4; ++mi)
      #pragma unroll
      for (int ni = 0; ni < 4; ++ni)
        acc[mi][ni] = __builtin_amdgcn_mfma_f32_16x16x32_bf16(af[mi], bfr[ni], acc[mi][ni], 0, 0, 0);
  }
  #pragma unroll
  for (int ni = 0; ni < 4; ++ni) {
    int col = colBase + wn * 64 + ni * 16 + lr;
    float bv = bias[col];
    #pragma unroll
    for (int mi = 0; mi < 4; ++mi) {
      #pragma unroll
      for (int jj = 0; jj < 4; ++jj) {
        int row2 = rowBase + wm * 64 + mi * 16 + lg * 4 + jj;
        float v = acc[mi][ni][jj] + bv;
        if constexpr (ACT == 1) v = gelu_fast(v);
        if constexpr (HASRES)   v += res[(size_t)row2 * N + col];
        out[(size_t)row2 * N + col] = (TO)v;
      }
    }
  }
}

// ---------------------------------------------------------------------------
// Flash attention v8 (r18-final): 32x32 MFMA, max-free exp2 softmax,
// cvt_pk + permlane32_swap in-register P, addrspace(3)-forced LDS access.
// ---------------------------------------------------------------------------
#define MKFRAG(S, T, OUT) do { \
    int a_, b_, c_, d_; \
    asm("v_cvt_pk_bf16_f32 %0, %1, %2" : "=v"(a_) : "v"((S)[8*(T)+0]), "v"((S)[8*(T)+1])); \
    asm("v_cvt_pk_bf16_f32 %0, %1, %2" : "=v"(b_) : "v"((S)[8*(T)+4]), "v"((S)[8*(T)+5])); \
    asm("v_cvt_pk_bf16_f32 %0, %1, %2" : "=v"(c_) : "v"((S)[8*(T)+2]), "v"((S)[8*(T)+3])); \
    asm("v_cvt_pk_bf16_f32 %0, %1, %2" : "=v"(d_) : "v"((S)[8*(T)+6]), "v"((S)[8*(T)+7])); \
    asm("v_permlane32_swap_b32 %0, %1" : "+v"(a_), "+v"(b_)); \
    asm("v_permlane32_swap_b32 %0, %1" : "+v"(c_), "+v"(d_)); \
    i32x4 wv_ = {a_, c_, b_, d_}; \
    OUT = __builtin_bit_cast(bf16x8, wv_); \
  } while (0)

#define ATILE(BO, DOLOAD, DOSTAGE) do { \
    if (DOLOAD) { \
      kg0 = *(const bf16x8*)kp0; kp0 += step; \
      kg1 = *(const bf16x8*)kp1; kp1 += step; \
      vg0 = *(const bf16x8*)vp0; \
      vg1 = *(const bf16x8*)(vp0 + 32); vp0 += step; \
    } \
    bf16x8 ka[2][4]; \
    _Pragma("unroll") for (int kb = 0; kb < 2; ++kb) \
      _Pragma("unroll") for (int dk = 0; dk < 4; ++dk) \
        ka[kb][dk] = lds_rd8(abase + (BO) + kb * 4096 + doff[dk]); \
    f32x16 sc0 = zz, sc1 = zz; \
    __builtin_amdgcn_s_setprio(1); \
    _Pragma("unroll") for (int dk = 0; dk < 4; ++dk) { \
      sc0 = __builtin_amdgcn_mfma_f32_32x32x16_bf16(ka[0][dk], qf[dk], sc0, 0, 0, 0); \
      sc1 = __builtin_amdgcn_mfma_f32_32x32x16_bf16(ka[1][dk], qf[dk], sc1, 0, 0, 0); \
    } \
    __builtin_amdgcn_s_setprio(0); \
    _Pragma("unroll") for (int r = 0; r < 16; ++r) sc0[r] = exp2f(sc0[r]); \
    _Pragma("unroll") for (int r = 0; r < 16; ++r) sc1[r] = exp2f(sc1[r]); \
    { \
      float t0_ = (sc0[0] + sc0[1]) + (sc0[2] + sc0[3]); \
      float t1_ = (sc0[4] + sc0[5]) + (sc0[6] + sc0[7]); \
      float t2_ = (sc0[8] + sc0[9]) + (sc0[10] + sc0[11]); \
      float t3_ = (sc0[12] + sc0[13]) + (sc0[14] + sc0[15]); \
      float t4_ = (sc1[0] + sc1[1]) + (sc1[2] + sc1[3]); \
      float t5_ = (sc1[4] + sc1[5]) + (sc1[6] + sc1[7]); \
      float t6_ = (sc1[8] + sc1[9]) + (sc1[10] + sc1[11]); \
      float t7_ = (sc1[12] + sc1[13]) + (sc1[14] + sc1[15]); \
      float rs = ((t0_ + t1_) + (t2_ + t3_)) + ((t4_ + t5_) + (t6_ + t7_)); \
      rs += __shfl_xor(rs, 32); \
      srow += rs; \
    } \
    bf16x8 pa0, pa1, pa2, pa3; \
    MKFRAG(sc0, 0, pa0); MKFRAG(sc0, 1, pa1); \
    MKFRAG(sc1, 0, pa2); MKFRAG(sc1, 1, pa3); \
    bf16x8 vb[2][4]; \
    _Pragma("unroll") for (int db = 0; db < 2; ++db) \
      _Pragma("unroll") for (int ks = 0; ks < 4; ++ks) \
        vb[db][ks] = lds_rd8(vbase + (BO) + db * 4096 + doff[ks]); \
    __builtin_amdgcn_s_setprio(1); \
    oa0 = __builtin_amdgcn_mfma_f32_32x32x16_bf16(pa0, vb[0][0], oa0, 0, 0, 0); \
    oa0 = __builtin_amdgcn_mfma_f32_32x32x16_bf16(pa1, vb[0][1], oa0, 0, 0, 0); \
    oa0 = __builtin_amdgcn_mfma_f32_32x32x16_bf16(pa2, vb[0][2], oa0, 0, 0, 0); \
    oa0 = __builtin_amdgcn_mfma_f32_32x32x16_bf16(pa3, vb[0][3], oa0, 0, 0, 0); \
    oa1 = __builtin_amdgcn_mfma_f32_32x32x16_bf16(pa0, vb[1][0], oa1, 0, 0, 0); \
    oa1 = __builtin_amdgcn_mfma_f32_32x32x16_bf16(pa1, vb[1][1], oa1, 0, 0, 0); \
    oa1 = __builtin_amdgcn_mfma_f32_32x32x16_bf16(pa2, vb[1][2], oa1, 0, 0, 0); \
    oa1 = __builtin_amdgcn_mfma_f32_32x32x16_bf16(pa3, vb[1][3], oa1, 0, 0, 0); \
    __builtin_amdgcn_s_setprio(0); \
    if (DOSTAGE) { \
      lds_wr8(ksw + ((BO) ^ 8192), kg0); \
      lds_wr8(ksw + 4096 + ((BO) ^ 8192), kg1); \
      _Pragma("unroll") for (int e = 0; e < 8; ++e) { \
        lds_wr1(vtw + ((BO) ^ 8192) + e * 128 + (l2 ^ (e << 4)), vg0[e]); \
        lds_wr1(vtw + ((BO) ^ 8192) + 4096 + e * 128 + (l2 ^ (e << 4)), vg1[e]); \
      } \
      __syncthreads(); \
    } \
  } while (0)

__global__ __launch_bounds__(256) void attn_kernel(const bf16* __restrict__ qkv,
                                                   bf16* __restrict__ o) {
  const int Nn = 2048, C3 = 3072;
  int tid = threadIdx.x, w = tid >> 6, l = tid & 63;
  int q32 = l & 31, hi = l >> 5, hi4 = hi * 4;
  int lin = blockIdx.x;                          // 512 blocks = 8 XCD x 64
  int wg = (lin & 7) * 64 + (lin >> 3);
  int qb = wg & 15, bh = wg >> 4;
  int b = bh >> 4, h = bh & 15;
  size_t hb = (size_t)b * Nn * C3 + h * 64;
  const bf16* Qp = qkv + hb;
  __shared__ bf16 Ks[2][64 * 64];
  __shared__ bf16 Vt[2][64 * 64];

  int q0w = qb * 128 + w * 32;
  bf16x8 qf[4];
  {
    const bf16* qrow = Qp + (size_t)(q0w + q32) * C3 + 8 * hi;
    #pragma unroll
    for (int dk = 0; dk < 4; ++dk) {
      bf16x8 t = *(const bf16x8*)(qrow + 16 * dk);
      #pragma unroll
      for (int e = 0; e < 8; ++e) qf[dk][e] = (bf16)((float)t[e] * 0.18033688f);
    }
  }

  int swz = (l & 7) << 4;
  int kr0 = tid >> 3, c80 = (tid & 7) * 8;
  char* ksw = (char*)Ks + kr0 * 128 + ((c80 * 2) ^ ((kr0 & 7) << 4));
  char* vtw = (char*)Vt + w * 1024;
  int l2 = l * 2;
  const char* abase = (const char*)Ks + q32 * 128;
  const char* vbase = (const char*)Vt + q32 * 128;
  int doff[4];
  #pragma unroll
  for (int dk = 0; dk < 4; ++dk) doff[dk] = (32 * dk + 16 * hi) ^ swz;

  const bf16* kp0 = qkv + hb + 1024 + (size_t)kr0 * C3 + c80;
  const bf16* kp1 = kp0 + (size_t)32 * C3;
  const bf16* vp0 = qkv + hb + 2048 + (size_t)l * C3 + w * 8;
  const int step = 64 * C3;

  f32x16 zz;
  #pragma unroll
  for (int i = 0; i < 16; ++i) zz[i] = 0.f;
  f32x16 oa0 = zz, oa1 = zz;
  float srow = 0.f;

  bf16x8 kg0 = *(const bf16x8*)kp0; kp0 += step;
  bf16x8 kg1 = *(const bf16x8*)kp1; kp1 += step;
  bf16x8 vg0 = *(const bf16x8*)vp0;
  bf16x8 vg1 = *(const bf16x8*)(vp0 + 32); vp0 += step;
  lds_wr8(ksw, kg0);
  lds_wr8(ksw + 4096, kg1);
  #pragma unroll
  for (int e = 0; e < 8; ++e) {
    lds_wr1(vtw + e * 128 + (l2 ^ (e << 4)), vg0[e]);
    lds_wr1(vtw + 4096 + e * 128 + (l2 ^ (e << 4)), vg1[e]);
  }
  __syncthreads();

  for (int tt = 0; tt < 16; ++tt) {
    ATILE(0,    true,     true);
    ATILE(8192, tt < 15,  tt < 15);
  }

  float inv = 1.f / srow;
  bf16* ob = o + ((size_t)b * Nn + q0w + hi4) * 1024 + h * 64 + q32;
  #pragma unroll
  for (int r = 0; r < 16; ++r) {
    const int cr = (r & 3) + 8 * (r >> 2);
    float invr = __shfl(inv, cr + hi4);
    ob[(size_t)cr * 1024]      = (bf16)(oa0[r] * invr);
    ob[(size_t)cr * 1024 + 32] = (bf16)(oa1[r] * invr);
  }
}

// ---------------------------------------------------------------------------
extern "C" void kernel_launch(void* const* d_in, const int* in_sizes, int n_in,
                              void* d_out, int out_size, void* d_ws, size_t ws_size,
                              hipStream_t stream) {
  (void)in_sizes; (void)n_in; (void)out_size;
  const float* x     = (const float*)d_in[0];
  const float* ln1g  = (const float*)d_in[1];
  const float* ln1b  = (const float*)d_in[2];
  const float* qkvw  = (const float*)d_in[3];
  const float* qkvb  = (const float*)d_in[4];
  const float* projw = (const float*)d_in[5];
  const float* projb = (const float*)d_in[6];
  const float* ln2g  = (const float*)d_in[7];
  const float* ln2b  = (const float*)d_in[8];
  const float* fc1w  = (const float*)d_in[9];
  const float* fc1b  = (const float*)d_in[10];
  const float* fc2w  = (const float*)d_in[11];
  const float* fc2b  = (const float*)d_in[12];

  char* ws = (char*)d_ws;
  bf16*  qkvw_h = (bf16*)(ws);                    // [0,  6M)
  bf16*  projw_h= (bf16*)(ws + (6ull  << 20));    // [6,  8M)
  bf16*  fc1w_h = (bf16*)(ws + (8ull  << 20));    // [8, 16M)
  bf16*  fc2w_h = (bf16*)(ws + (16ull << 20));    // [16,24M)
  bf16*  h1     = (bf16*)(ws + (24ull << 20));    // [24,32M)  (reused for h2)
  bf16*  qkv    = (bf16*)(ws + (32ull << 20));    // [32,64M)  (reused for ffn)
  bf16*  ov     = (bf16*)(ws + (64ull << 20));    // [64,72M)
  float* x1     = (float*)(ws + (72ull << 20));   // [72,88M)  fp32 residual trunk
  bf16*  parts  = (bf16*)(ws + (96ull << 20));    // [96,128M) proj/fc2 partials
  bf16*  h2  = h1;
  bf16*  ffn = qkv;
  bool big = ws_size >= (160ull << 20);

  const int M = 4096;
  prep<<<dim3(12288 + 1024), 256, 0, stream>>>(qkvw, projw, fc1w, fc2w,
      qkvw_h, projw_h, fc1w_h, fc2w_h, x, ln1g, ln1b, h1);
  gemm256<0, 1, bf16><<<dim3(192), dim3(512), 0, stream>>>(
      h1, qkvw_h, qkvb, qkv, 1024, 3072, 1024, 12, 0);
  attn_kernel<<<dim3(512), 256, 0, stream>>>(qkv, ov);
  if (big) {
    gemm256<0, 0, bf16><<<dim3(64, 4), dim3(512), 0, stream>>>(
        ov, projw_h, nullptr, parts, 1024, 1024, 256, 4, 4194304ull);
    projred_ln<<<dim3(1024), 256, 0, stream>>>(parts, x, projb, ln2g, ln2b, x1, h2);
  } else {
    gemm_bt<0, 1, float><<<dim3(8, 32), 256, 0, stream>>>(
        ov, projw_h, projb, x, x1, M, 1024, 1024);
    ln_f32<<<dim3(1024), 256, 0, stream>>>(x1, ln2g, ln2b, h2);
  }
  gemm256<1, 1, bf16><<<dim3(256), dim3(512), 0, stream>>>(
      h2, fc1w_h, fc1b, ffn, 1024, 4096, 1024, 16, 0);
  if (big) {
    gemm256<0, 0, bf16><<<dim3(64, 4), dim3(512), 0, stream>>>(
        ffn, fc2w_h, nullptr, parts, 4096, 1024, 1024, 4, 4194304ull);
    fc2_red<<<dim3(4096), 256, 0, stream>>>(parts, x1, fc2b, (float*)d_out);
  } else {
    gemm_bt<0, 1, float><<<dim3(8, 32), 256, 0, stream>>>(
        ffn, fc2w_h, fc2b, x1, (float*)d_out, M, 1024, 4096);
  }
}